// Round 1
// baseline (26.299 us; speedup 1.0000x reference)
//
#include <hip/hip_runtime.h>

// x: (512, 2048, 64) f32. Per row of 64 floats we need indices 0 (sign),
// 1 (e10), 11 (e0), 12 (m51), 13 (m50).
// Outputs concatenated flat in d_out: result (R, 2) f32 then sign (R, 1) f32.
// R = 512*2048 = 1,048,576.

__global__ void spike_extract_kernel(const float* __restrict__ x,
                                     float* __restrict__ result,
                                     float* __restrict__ sign_out,
                                     int nrows) {
    int row = blockIdx.x * blockDim.x + threadIdx.x;
    if (row >= nrows) return;

    const float4* base = reinterpret_cast<const float4*>(x + (size_t)row * 64);
    // All three chunks live in the row's first 64B cache line.
    float4 c0 = base[0];  // indices 0..3   -> sign, e10
    float4 c2 = base[2];  // indices 8..11  -> e0 (.w)
    float4 c3 = base[3];  // indices 12..15 -> m51 (.x), m50 (.y)

    float s   = c0.x;
    float e10 = c0.y;
    float e0  = c2.w;
    float m51 = c3.x;
    float m50 = c3.y;

    // _mux(sel, a, b) = b + sel*(a - b)
    float b0_high = fmaf(e0, m50 - m51, m51);   // mux(e0, m50, m51)
    float b1_high = fmaf(e0, m51 - 1.0f, 1.0f); // mux(e0, m51, 1)
    float b0      = fmaf(e10, b0_high - e0, e0);// mux(e10, b0_high, e0)
    float b1      = e10 * b1_high;              // mux(e10, b1_high, 0)

    // result layout: (..., 2) = [b1, b0] per row, contiguous.
    reinterpret_cast<float2*>(result)[row] = make_float2(b1, b0);
    sign_out[row] = s;
}

extern "C" void kernel_launch(void* const* d_in, const int* in_sizes, int n_in,
                              void* d_out, int out_size, void* d_ws, size_t ws_size,
                              hipStream_t stream) {
    const float* x = (const float*)d_in[0];
    float* out = (float*)d_out;

    int nrows = in_sizes[0] / 64;          // 1,048,576
    float* result = out;                   // nrows * 2 floats
    float* sign_out = out + (size_t)nrows * 2;

    const int block = 256;
    const int grid = (nrows + block - 1) / block;  // 4096 blocks
    spike_extract_kernel<<<grid, block, 0, stream>>>(x, result, sign_out, nrows);
}